// Round 17
// baseline (143.922 us; speedup 1.0000x reference)
//
#include <hip/hip_runtime.h>
#include <hip/hip_bf16.h>

#define B_ 16
#define C_ 256
#define N_ 16384      // 128*128
#define WT_ 128       // n per kA tile
#define TPB_ 128      // tiles per batch = N_/WT_
#define R16_ 16
#define TLSTR_ 66     // tile row stride in dwords

typedef float f32x4 __attribute__((ext_vector_type(4)));

__device__ __forceinline__ float4 ldf4(const float* p) {
    return *reinterpret_cast<const float4*>(p);
}
__device__ __forceinline__ float bfl(unsigned p) {  // low bf16 -> f32
    return __uint_as_float(p << 16);
}
__device__ __forceinline__ float bfh(unsigned p) {  // high bf16 -> f32
    return __uint_as_float(p & 0xFFFF0000u);
}

// ---------------------------------------------------------------------------
// kA: fused stats pass (R16 structure) + persists the bf16 x-copy to global.
// The packed pairs (already produced for the LDS tile) are also stored into
// the FIRST HALF of each d_out row: row (b,c)'s dwords [0,8192) hold bf16
// pairs, dword D covers n=2D,2D+1.  kC later consumes them (half the read
// bytes of fp32 x) and overwrites the row.  xbf writes are regular (L3
// allocate) so kC's reverse-order read hits MRU lines.
// ---------------------------------------------------------------------------
__global__ __launch_bounds__(512, 4)
void kA(const float* __restrict__ x,
        float* __restrict__ Ppart,
        float* __restrict__ RSpart,
        unsigned* __restrict__ xbf) {          // aliases d_out (dword view)
    __shared__ unsigned tl[C_ * TLSTR_];    // bf16 tile as dwords
    __shared__ float4 csp[8][2][32];        // [wave][half][n4] colsum partials
    __shared__ float colsum[WT_];
    __shared__ float2 phalf[C_];            // phase-B half exchange

    const int tile = blockIdx.x;    // 0..127
    const int b = blockIdx.y;
    const int t = threadIdx.x;      // 0..511
    const int lane = t & 63;
    const int w = t >> 6;           // wave 0..7
    const int h = lane >> 5;        // half-wave 0/1
    const int ln = lane & 31;       // lane-in-half

    const float* xt = x + (size_t)b * C_ * N_ + tile * WT_ + (ln << 2);
    const int c0 = (w << 5) + h;

    // ---- phase A: stream 16 rows, pack bf16 -> LDS tile + global xbf copy
    float4 cs = make_float4(0.f, 0.f, 0.f, 0.f);
#pragma unroll
    for (int k = 0; k < 16; ++k) {
        const int c = c0 + (k << 1);
        float4 v = ldf4(xt + (size_t)c * N_);
        cs.x += v.x; cs.y += v.y; cs.z += v.z; cs.w += v.w;
        __hip_bfloat162 lo = __float22bfloat162_rn(make_float2(v.x, v.y));
        __hip_bfloat162 hi = __float22bfloat162_rn(make_float2(v.z, v.w));
        const unsigned ulo = *reinterpret_cast<unsigned*>(&lo);
        const unsigned uhi = *reinterpret_cast<unsigned*>(&hi);
        unsigned* dst = tl + c * TLSTR_ + (ln << 1);
        dst[0] = ulo;
        dst[1] = uhi;
        // global bf16 copy: row (b,c), dword offset n/2 = tile*64 + 2*ln
        uint2 pk2; pk2.x = ulo; pk2.y = uhi;
        *reinterpret_cast<uint2*>(
            xbf + (size_t)(b * C_ + c) * (size_t)N_ + tile * (WT_ / 2) + (ln << 1)) = pk2;
    }
    csp[w][h][ln] = cs;
    __syncthreads();

    // ---- colsum[n]: threads 0..31 sum the 16 wave/half partials (f4-wise)
    if (t < 32) {
        float4 s = make_float4(0.f, 0.f, 0.f, 0.f);
#pragma unroll
        for (int w2 = 0; w2 < 8; ++w2) {
#pragma unroll
            for (int h2 = 0; h2 < 2; ++h2) {
                float4 p = csp[w2][h2][t];
                s.x += p.x; s.y += p.y; s.z += p.z; s.w += p.w;
            }
        }
        *reinterpret_cast<float4*>(&colsum[t << 2]) = s;
    }
    __syncthreads();

    // ---- phase B: thread t owns (c = t&255, half hh = t>>8); 32 dwords
    const int c = t & 255, hh = t >> 8;
    const unsigned* row = tl + c * TLSTR_ + (hh << 5);
    const float* csq = colsum + (hh << 6);
    float P = 0.f, RS = 0.f;
#pragma unroll
    for (int j = 0; j < 32; ++j) {
        const unsigned pk = row[j];
        const float vx = bfl(pk), vy = bfh(pk);
        P += vx * csq[2 * j] + vy * csq[2 * j + 1];
        RS += vx + vy;
    }
    if (hh) phalf[c] = make_float2(P, RS);
    __syncthreads();
    if (t < C_) {
        P += phalf[t].x;
        RS += phalf[t].y;
        const size_t base = ((size_t)b * TPB_ + tile) * C_;
        Ppart [base + t] = P;
        RSpart[base + t] = RS;
    }
}

// ---------------------------------------------------------------------------
// kB: reduce 128 partials -> v -> fused MLP -> gate.  grid(B_) x 256.
// ---------------------------------------------------------------------------
__global__ void kB(const float* __restrict__ Ppart,
                   const float* __restrict__ RSpart,
                   const float* __restrict__ w1, const float* __restrict__ b1,
                   const float* __restrict__ w2, const float* __restrict__ b2,
                   float* __restrict__ gate) {
    const int b = blockIdx.x;
    const int t = threadIdx.x;   // channel c

    float P = 0.f, RS = 0.f;
#pragma unroll 8
    for (int k = 0; k < TPB_; ++k) {
        P  += Ppart [((size_t)b * TPB_ + k) * C_ + t];
        RS += RSpart[((size_t)b * TPB_ + k) * C_ + t];
    }

    __shared__ float red[4];
    float s = RS;
#pragma unroll
    for (int off = 32; off; off >>= 1) s += __shfl_down(s, off, 64);
    if ((t & 63) == 0) red[t >> 6] = s;
    __syncthreads();
    const float T = red[0] + red[1] + red[2] + red[3];
    const float M = T / (float)N_;
    const float denom = (float)(N_ - 1) * (float)C_;

    __shared__ float vl[C_];
    vl[t] = (P - M * RS) / denom;
    __syncthreads();

    __shared__ float hpart[R16_][16];
    __shared__ float h1[R16_];
    {
        const int i = t >> 4, cc = t & 15;
        float a = 0.f;
#pragma unroll
        for (int k = 0; k < 16; ++k)
            a += vl[(cc << 4) + k] * w1[i * C_ + (cc << 4) + k];
        hpart[i][cc] = a;
    }
    __syncthreads();
    if (t < R16_) {
        float a = b1[t];
#pragma unroll
        for (int k = 0; k < 16; ++k) a += hpart[t][k];
        h1[t] = a > 0.f ? a : 0.f;
    }
    __syncthreads();

    float a = b2[t];
#pragma unroll
    for (int i = 0; i < R16_; ++i) a += h1[i] * w2[t * R16_ + i];
    gate[b * C_ + t] = 1.f / (1.f + __expf(-a));
}

// ---------------------------------------------------------------------------
// kC: out = bf16(x) * gate, reading the bf16 copy from its own row's first
// half (written by kA), then overwriting the row with fp32 results.
// Race-free per block: all reads -> __syncthreads (drains vmcnt) -> writes.
// Reverse row order: kA wrote xbf forward, so reverse read = MRU-first L3.
// ---------------------------------------------------------------------------
__global__ __launch_bounds__(256)
void kC(const unsigned* __restrict__ xbf,   // aliases d_out (dword view)
        const float* __restrict__ gate,
        float* __restrict__ out) {
    const int nrows = B_ * C_;              // 4096 rows of 16384 floats
    const int t = threadIdx.x;
    for (int row = blockIdx.x; row < nrows; row += gridDim.x) {
        const int rr = nrows - 1 - row;     // reverse traversal
        const float g = gate[rr];
        const unsigned* src = xbf + (size_t)rr * (size_t)N_;
        f32x4* dst = reinterpret_cast<f32x4*>(out) + (size_t)rr * 4096;

        uint2 buf[16];
#pragma unroll
        for (int j = 0; j < 16; ++j)
            buf[j] = *reinterpret_cast<const uint2*>(src + j * 512 + (t << 1));
        __syncthreads();                    // all row reads done before writes
#pragma unroll
        for (int j = 0; j < 16; ++j) {
            f32x4 r;
            r.x = bfl(buf[j].x) * g;
            r.y = bfh(buf[j].x) * g;
            r.z = bfl(buf[j].y) * g;
            r.w = bfh(buf[j].y) * g;
            __builtin_nontemporal_store(r, dst + j * 256 + t);
        }
    }
}

extern "C" void kernel_launch(void* const* d_in, const int* in_sizes, int n_in,
                              void* d_out, int out_size, void* d_ws, size_t ws_size,
                              hipStream_t stream) {
    (void)in_sizes; (void)n_in; (void)out_size; (void)ws_size;
    const float* x  = (const float*)d_in[0];
    const float* w1 = (const float*)d_in[1];
    const float* b1 = (const float*)d_in[2];
    const float* w2 = (const float*)d_in[3];
    const float* b2 = (const float*)d_in[4];
    float* out = (float*)d_out;

    float* ws     = (float*)d_ws;
    float* Ppart  = ws;                                    // B_*TPB_*C_ = 524288
    float* RSpart = Ppart + (size_t)B_ * TPB_ * C_;        // 524288
    float* gate   = RSpart + (size_t)B_ * TPB_ * C_;       // B_*C_

    hipLaunchKernelGGL(kA, dim3(TPB_, B_), dim3(512), 0, stream,
                       x, Ppart, RSpart, (unsigned*)d_out);
    hipLaunchKernelGGL(kB, dim3(B_), dim3(256), 0, stream,
                       Ppart, RSpart, w1, b1, w2, b2, gate);
    hipLaunchKernelGGL(kC, dim3(2048), dim3(256), 0, stream,
                       (const unsigned*)d_out, gate, out);
}

// Round 18
// 141.182 us; speedup vs baseline: 1.0194x; 1.0194x over previous
//
#include <hip/hip_runtime.h>
#include <hip/hip_bf16.h>

#define B_ 16
#define C_ 256
#define N_ 16384      // 128*128
#define WT_ 128       // n per kA tile
#define TPB_ 128      // tiles per batch = N_/WT_
#define R16_ 16
#define TLSTR_ 68     // tile row stride in dwords (272B, 16B-aligned rows)

typedef float f32x4 __attribute__((ext_vector_type(4)));

__device__ __forceinline__ float4 ldf4(const float* p) {
    return *reinterpret_cast<const float4*>(p);
}
__device__ __forceinline__ float bfl(unsigned p) {  // low bf16 -> f32
    return __uint_as_float(p << 16);
}
__device__ __forceinline__ float bfh(unsigned p) {  // high bf16 -> f32
    return __uint_as_float(p & 0xFFFF0000u);
}

// ---------------------------------------------------------------------------
// kA: fused stats pass (R16 streaming structure) with LDS-instruction-count
// fixes: XOR-swizzled tile (d' = d ^ ((c&7)<<2), same involution on store
// and load), ds_write_b64 staging, ds_read_b128 phase-B (8 instead of 32
// LDS reads/thread), broadcast colsum reads.  LDS ~79 KiB -> 2 blocks/CU.
// P/RS from bf16 copy (R12-R17 proven: absmax unchanged).
// ---------------------------------------------------------------------------
__global__ __launch_bounds__(512, 4)
void kA(const float* __restrict__ x,
        float* __restrict__ Ppart,
        float* __restrict__ RSpart) {
    __shared__ unsigned tl[C_ * TLSTR_];    // bf16 tile as dwords, swizzled
    __shared__ float4 csp[8][2][32];        // [wave][half][n4] colsum partials
    __shared__ float colsum[WT_];
    __shared__ float2 phalf[C_];            // phase-B half exchange

    const int tile = blockIdx.x;    // 0..127
    const int b = blockIdx.y;
    const int t = threadIdx.x;      // 0..511
    const int lane = t & 63;
    const int w = t >> 6;           // wave 0..7
    const int h = lane >> 5;        // half-wave 0/1
    const int ln = lane & 31;       // lane-in-half

    const float* xt = x + (size_t)b * C_ * N_ + tile * WT_ + (ln << 2);
    const int c0 = (w << 5) + h;

    // ---- phase A: stream 16 rows (2 channels per wave-load), pack to bf16
    float4 cs = make_float4(0.f, 0.f, 0.f, 0.f);
#pragma unroll
    for (int k = 0; k < 16; ++k) {
        const int c = c0 + (k << 1);
        float4 v = ldf4(xt + (size_t)c * N_);
        cs.x += v.x; cs.y += v.y; cs.z += v.z; cs.w += v.w;
        __hip_bfloat162 lo = __float22bfloat162_rn(make_float2(v.x, v.y));
        __hip_bfloat162 hi = __float22bfloat162_rn(make_float2(v.z, v.w));
        uint2 pk2;
        pk2.x = *reinterpret_cast<unsigned*>(&lo);
        pk2.y = *reinterpret_cast<unsigned*>(&hi);
        // logical dword pair d = 2*ln; swizzled d' = d ^ ((c&7)<<2)
        const int d = (ln << 1) ^ ((c & 7) << 2);
        *reinterpret_cast<uint2*>(&tl[c * TLSTR_ + d]) = pk2;   // ds_write_b64
    }
    csp[w][h][ln] = cs;
    __syncthreads();

    // ---- colsum[n]: threads 0..31 sum the 16 wave/half partials (f4-wise)
    if (t < 32) {
        float4 s = make_float4(0.f, 0.f, 0.f, 0.f);
#pragma unroll
        for (int w2 = 0; w2 < 8; ++w2) {
#pragma unroll
            for (int h2 = 0; h2 < 2; ++h2) {
                float4 p = csp[w2][h2][t];
                s.x += p.x; s.y += p.y; s.z += p.z; s.w += p.w;
            }
        }
        *reinterpret_cast<float4*>(&colsum[t << 2]) = s;
    }
    __syncthreads();

    // ---- phase B: thread t owns (c = t&255, half hh = t>>8)
    // 8 x ds_read_b128: group g = hh*8+j, physical base (g<<2)^swz.
    const int c = t & 255, hh = t >> 8;
    const int swz = (c & 7) << 2;
    const unsigned* rowbase = tl + c * TLSTR_;
    float P = 0.f, RS = 0.f;
#pragma unroll
    for (int j = 0; j < 8; ++j) {
        const int g = (hh << 3) + j;
        const uint4 q = *reinterpret_cast<const uint4*>(rowbase + (((g << 2) ^ swz)));
        const float4 ca = *reinterpret_cast<const float4*>(&colsum[(g << 3)]);
        const float4 cb = *reinterpret_cast<const float4*>(&colsum[(g << 3) + 4]);
        P += bfl(q.x) * ca.x + bfh(q.x) * ca.y
           + bfl(q.y) * ca.z + bfh(q.y) * ca.w
           + bfl(q.z) * cb.x + bfh(q.z) * cb.y
           + bfl(q.w) * cb.z + bfh(q.w) * cb.w;
        RS += bfl(q.x) + bfh(q.x) + bfl(q.y) + bfh(q.y)
            + bfl(q.z) + bfh(q.z) + bfl(q.w) + bfh(q.w);
    }
    if (hh) phalf[c] = make_float2(P, RS);
    __syncthreads();
    if (t < C_) {
        P += phalf[t].x;
        RS += phalf[t].y;
        const size_t base = ((size_t)b * TPB_ + tile) * C_;
        Ppart [base + t] = P;
        RSpart[base + t] = RS;
    }
}

// ---------------------------------------------------------------------------
// kB: reduce 128 partials -> v -> fused MLP -> gate.  grid(B_) x 256.
// ---------------------------------------------------------------------------
__global__ void kB(const float* __restrict__ Ppart,
                   const float* __restrict__ RSpart,
                   const float* __restrict__ w1, const float* __restrict__ b1,
                   const float* __restrict__ w2, const float* __restrict__ b2,
                   float* __restrict__ gate) {
    const int b = blockIdx.x;
    const int t = threadIdx.x;   // channel c

    float P = 0.f, RS = 0.f;
#pragma unroll 8
    for (int k = 0; k < TPB_; ++k) {
        P  += Ppart [((size_t)b * TPB_ + k) * C_ + t];
        RS += RSpart[((size_t)b * TPB_ + k) * C_ + t];
    }

    __shared__ float red[4];
    float s = RS;
#pragma unroll
    for (int off = 32; off; off >>= 1) s += __shfl_down(s, off, 64);
    if ((t & 63) == 0) red[t >> 6] = s;
    __syncthreads();
    const float T = red[0] + red[1] + red[2] + red[3];
    const float M = T / (float)N_;
    const float denom = (float)(N_ - 1) * (float)C_;

    __shared__ float vl[C_];
    vl[t] = (P - M * RS) / denom;
    __syncthreads();

    __shared__ float hpart[R16_][16];
    __shared__ float h1[R16_];
    {
        const int i = t >> 4, cc = t & 15;
        float a = 0.f;
#pragma unroll
        for (int k = 0; k < 16; ++k)
            a += vl[(cc << 4) + k] * w1[i * C_ + (cc << 4) + k];
        hpart[i][cc] = a;
    }
    __syncthreads();
    if (t < R16_) {
        float a = b1[t];
#pragma unroll
        for (int k = 0; k < 16; ++k) a += hpart[t][k];
        h1[t] = a > 0.f ? a : 0.f;
    }
    __syncthreads();

    float a = b2[t];
#pragma unroll
    for (int i = 0; i < R16_; ++i) a += h1[i] * w2[t * R16_ + i];
    gate[b * C_ + t] = 1.f / (1.f + __expf(-a));
}

// ---------------------------------------------------------------------------
// kC: out = x * gate[b,c], reverse traversal (boustrophedon) + nt stores.
// ---------------------------------------------------------------------------
__global__ void kC(const float* __restrict__ x,
                   const float* __restrict__ gate,
                   float* __restrict__ out) {
    const int nrows = B_ * C_;           // 4096 rows of 4096 float4
    for (int row = blockIdx.x; row < nrows; row += gridDim.x) {
        const int rr = nrows - 1 - row;  // reverse traversal
        const float g = gate[rr];
        const float4* src = reinterpret_cast<const float4*>(x) + (size_t)rr * 4096;
        f32x4* dst = reinterpret_cast<f32x4*>(out) + (size_t)rr * 4096;
        for (int i = threadIdx.x; i < 4096; i += blockDim.x) {
            float4 vx = src[i];
            f32x4 r;
            r.x = vx.x * g; r.y = vx.y * g; r.z = vx.z * g; r.w = vx.w * g;
            __builtin_nontemporal_store(r, dst + i);
        }
    }
}

extern "C" void kernel_launch(void* const* d_in, const int* in_sizes, int n_in,
                              void* d_out, int out_size, void* d_ws, size_t ws_size,
                              hipStream_t stream) {
    (void)in_sizes; (void)n_in; (void)out_size; (void)ws_size;
    const float* x  = (const float*)d_in[0];
    const float* w1 = (const float*)d_in[1];
    const float* b1 = (const float*)d_in[2];
    const float* w2 = (const float*)d_in[3];
    const float* b2 = (const float*)d_in[4];
    float* out = (float*)d_out;

    float* ws     = (float*)d_ws;
    float* Ppart  = ws;                                    // B_*TPB_*C_ = 524288
    float* RSpart = Ppart + (size_t)B_ * TPB_ * C_;        // 524288
    float* gate   = RSpart + (size_t)B_ * TPB_ * C_;       // B_*C_

    hipLaunchKernelGGL(kA, dim3(TPB_, B_), dim3(512), 0, stream,
                       x, Ppart, RSpart);
    hipLaunchKernelGGL(kB, dim3(B_), dim3(256), 0, stream,
                       Ppart, RSpart, w1, b1, w2, b2, gate);
    hipLaunchKernelGGL(kC, dim3(2048), dim3(256), 0, stream,
                       x, gate, out);
}

// Round 19
// 139.199 us; speedup vs baseline: 1.0339x; 1.0142x over previous
//
#include <hip/hip_runtime.h>
#include <hip/hip_bf16.h>

#define B_ 16
#define C_ 256
#define N_ 16384      // 128*128
#define WT_ 256       // n per kA tile
#define TPB_ 64       // tiles per batch = N_/WT_
#define R16_ 16
#define TLSTR_ 129    // tile row stride in dwords (odd -> phase-B 2-way max)

typedef float f32x4 __attribute__((ext_vector_type(4)));

__device__ __forceinline__ float4 ldf4(const float* p) {
    return *reinterpret_cast<const float4*>(p);
}
__device__ __forceinline__ float bfl(unsigned p) {  // low bf16 -> f32
    return __uint_as_float(p << 16);
}
__device__ __forceinline__ float bfh(unsigned p) {  // high bf16 -> f32
    return __uint_as_float(p & 0xFFFF0000u);
}

// ---------------------------------------------------------------------------
// kA: fused stats pass (session-best R15 config).  1024 thr = 16 waves,
// tile = x[b, 0:256, n0:n0+256].  Phase A: wave w streams rows 16w..16w+15,
// one float4/lane -> contiguous 1-KiB wave segments; colsum in f4 reg;
// values packed bf16 (cvt_pk) into the dynamic-LDS tile (129-dword stride).
// Phase B: thread t dots row (t&255), quarter (t>>8) against colsum.
// LDS: 129 KiB dynamic + 23.5 KiB static -> 1 block/CU, 16 waves.
// P/RS from bf16 copy (R12-R18 proven: absmax unchanged vs fp32).
// ---------------------------------------------------------------------------
__global__ __launch_bounds__(1024)
void kA(const float* __restrict__ x,
        float* __restrict__ Ppart,
        float* __restrict__ RSpart) {
    extern __shared__ ushort tl[];          // [256][258] bf16, stride 129 dw
    __shared__ float4 csp[16][64];          // per-wave colsum partials
    __shared__ float colsum[WT_];
    __shared__ float2 pq[3][C_];            // phase-B quarter exchange

    const int tile = blockIdx.x;    // 0..63
    const int b = blockIdx.y;
    const int t = threadIdx.x;      // 0..1023
    const int lane = t & 63;
    const int w = t >> 6;           // wave 0..15

    const float* xt = x + (size_t)b * C_ * N_ + tile * WT_ + (lane << 2);
    const int c0 = w << 4;

    // ---- phase A: 16 contiguous 1-KiB wave loads, pack to bf16 tile
    float4 cs = make_float4(0.f, 0.f, 0.f, 0.f);
#pragma unroll
    for (int k = 0; k < 16; ++k) {
        const int c = c0 + k;
        float4 v = ldf4(xt + (size_t)c * N_);
        cs.x += v.x; cs.y += v.y; cs.z += v.z; cs.w += v.w;
        __hip_bfloat162 lo = __float22bfloat162_rn(make_float2(v.x, v.y));
        __hip_bfloat162 hi = __float22bfloat162_rn(make_float2(v.z, v.w));
        unsigned* dst = reinterpret_cast<unsigned*>(tl) + c * TLSTR_ + (lane << 1);
        dst[0] = *reinterpret_cast<unsigned*>(&lo);
        dst[1] = *reinterpret_cast<unsigned*>(&hi);
    }
    csp[w][lane] = cs;
    __syncthreads();

    // ---- colsum[n]: sum the 16 wave partials (t<256: n = t)
    if (t < WT_) {
        const float* base = reinterpret_cast<const float*>(&csp[0][t >> 2]) + (t & 3);
        float s = 0.f;
#pragma unroll
        for (int w2 = 0; w2 < 16; ++w2) s += base[w2 * 256];  // 64 f4 = 256 f
        colsum[t] = s;
    }
    __syncthreads();

    // ---- phase B: thread t owns (c = t&255, quarter q = t>>8)
    const int c = t & 255, q = t >> 8;
    const unsigned* row = reinterpret_cast<const unsigned*>(tl) + c * TLSTR_ + (q << 5);
    const float* csq = colsum + (q << 6);
    float P = 0.f, RS = 0.f;
#pragma unroll
    for (int j = 0; j < 32; ++j) {
        const unsigned pk = row[j];
        const float vx = bfl(pk), vy = bfh(pk);
        P += vx * csq[2 * j] + vy * csq[2 * j + 1];
        RS += vx + vy;
    }
    if (q) pq[q - 1][c] = make_float2(P, RS);
    __syncthreads();
    if (t < C_) {       // q == 0 threads finalize channel t
        P  += pq[0][t].x + pq[1][t].x + pq[2][t].x;
        RS += pq[0][t].y + pq[1][t].y + pq[2][t].y;
        const size_t base = ((size_t)b * TPB_ + tile) * C_;
        Ppart [base + t] = P;
        RSpart[base + t] = RS;
    }
}

// ---------------------------------------------------------------------------
// kB: reduce 64 partials -> v -> fused MLP -> gate.  grid(B_) x 256.
// ---------------------------------------------------------------------------
__global__ void kB(const float* __restrict__ Ppart,
                   const float* __restrict__ RSpart,
                   const float* __restrict__ w1, const float* __restrict__ b1,
                   const float* __restrict__ w2, const float* __restrict__ b2,
                   float* __restrict__ gate) {
    const int b = blockIdx.x;
    const int t = threadIdx.x;   // channel c

    float P = 0.f, RS = 0.f;
#pragma unroll 8
    for (int k = 0; k < TPB_; ++k) {
        P  += Ppart [((size_t)b * TPB_ + k) * C_ + t];
        RS += RSpart[((size_t)b * TPB_ + k) * C_ + t];
    }

    __shared__ float red[4];
    float s = RS;
#pragma unroll
    for (int off = 32; off; off >>= 1) s += __shfl_down(s, off, 64);
    if ((t & 63) == 0) red[t >> 6] = s;
    __syncthreads();
    const float T = red[0] + red[1] + red[2] + red[3];
    const float M = T / (float)N_;
    const float denom = (float)(N_ - 1) * (float)C_;

    __shared__ float vl[C_];
    vl[t] = (P - M * RS) / denom;
    __syncthreads();

    __shared__ float hpart[R16_][16];
    __shared__ float h1[R16_];
    {
        const int i = t >> 4, cc = t & 15;
        float a = 0.f;
#pragma unroll
        for (int k = 0; k < 16; ++k)
            a += vl[(cc << 4) + k] * w1[i * C_ + (cc << 4) + k];
        hpart[i][cc] = a;
    }
    __syncthreads();
    if (t < R16_) {
        float a = b1[t];
#pragma unroll
        for (int k = 0; k < 16; ++k) a += hpart[t][k];
        h1[t] = a > 0.f ? a : 0.f;
    }
    __syncthreads();

    float a = b2[t];
#pragma unroll
    for (int i = 0; i < R16_; ++i) a += h1[i] * w2[t * R16_ + i];
    gate[b * C_ + t] = 1.f / (1.f + __expf(-a));
}

// ---------------------------------------------------------------------------
// kC: out = x * gate[b,c], reverse traversal (boustrophedon) + nt stores.
// ---------------------------------------------------------------------------
__global__ void kC(const float* __restrict__ x,
                   const float* __restrict__ gate,
                   float* __restrict__ out) {
    const int nrows = B_ * C_;           // 4096 rows of 4096 float4
    for (int row = blockIdx.x; row < nrows; row += gridDim.x) {
        const int rr = nrows - 1 - row;  // reverse traversal
        const float g = gate[rr];
        const float4* src = reinterpret_cast<const float4*>(x) + (size_t)rr * 4096;
        f32x4* dst = reinterpret_cast<f32x4*>(out) + (size_t)rr * 4096;
        for (int i = threadIdx.x; i < 4096; i += blockDim.x) {
            float4 vx = src[i];
            f32x4 r;
            r.x = vx.x * g; r.y = vx.y * g; r.z = vx.z * g; r.w = vx.w * g;
            __builtin_nontemporal_store(r, dst + i);
        }
    }
}

extern "C" void kernel_launch(void* const* d_in, const int* in_sizes, int n_in,
                              void* d_out, int out_size, void* d_ws, size_t ws_size,
                              hipStream_t stream) {
    (void)in_sizes; (void)n_in; (void)out_size; (void)ws_size;
    const float* x  = (const float*)d_in[0];
    const float* w1 = (const float*)d_in[1];
    const float* b1 = (const float*)d_in[2];
    const float* w2 = (const float*)d_in[3];
    const float* b2 = (const float*)d_in[4];
    float* out = (float*)d_out;

    float* ws     = (float*)d_ws;
    float* Ppart  = ws;                                    // B_*TPB_*C_ = 262144
    float* RSpart = Ppart + (size_t)B_ * TPB_ * C_;        // 262144
    float* gate   = RSpart + (size_t)B_ * TPB_ * C_;       // B_*C_

    const int tl_bytes = C_ * (2 * TLSTR_) * (int)sizeof(ushort);  // 132096 B
    // allow >64 KiB dynamic LDS (host-side, idempotent, capture-safe)
    static bool attr_done = false;
    if (!attr_done) {
        hipFuncSetAttribute((const void*)kA,
                            hipFuncAttributeMaxDynamicSharedMemorySize,
                            tl_bytes);
        attr_done = true;
    }

    hipLaunchKernelGGL(kA, dim3(TPB_, B_), dim3(1024), tl_bytes, stream,
                       x, Ppart, RSpart);
    hipLaunchKernelGGL(kB, dim3(B_), dim3(256), 0, stream,
                       Ppart, RSpart, w1, b1, w2, b2, gate);
    hipLaunchKernelGGL(kC, dim3(2048), dim3(256), 0, stream,
                       x, gate, out);
}